// Round 3
// baseline (60.370 us; speedup 1.0000x reference)
//
#include <hip/hip_runtime.h>
#include <math.h>

#define FEAT 64

// Clang-native vector types (accepted by __builtin_nontemporal_*).
typedef float     f32x4 __attribute__((ext_vector_type(4)));
typedef int       i32x4 __attribute__((ext_vector_type(4)));
typedef long long i64x2 __attribute__((ext_vector_type(2)));

// One 64-lane wave per destination node.
// lane = (q = lane>>4 edge-quadrant, f4 = lane&15 float4-slot of the feature row).
// Each quadrant owns 4 contiguous edges; value rows are gathered as float4
// (16 lanes x 16B = one 256B row per quadrant per load instruction -> 1KB/wave/instr).
__global__ __launch_bounds__(256) void gat_agg_kernel(
    const void* __restrict__ row_ptr_v,
    const void* __restrict__ col_idx_v,
    const float* __restrict__ scores,
    const float* __restrict__ values,
    float* __restrict__ out,
    int num_nodes)
{
    const int wid  = blockIdx.x * 4 + (threadIdx.x >> 6);
    const int lane = threadIdx.x & 63;
    if (wid >= num_nodes) return;

    // Index width probe: int32 row_ptr has rp32[1]==DEGREE(>0); int64 has hi(rp[0])==0.
    const int* rp32 = (const int*)row_ptr_v;
    const bool idx64 = (rp32[1] == 0);

    long long start, end;
    if (idx64) {
        const long long* rp = (const long long*)row_ptr_v;
        start = rp[wid]; end = rp[wid + 1];
    } else {
        start = (long long)rp32[wid]; end = (long long)rp32[wid + 1];
    }
    const int deg = (int)(end - start);

    if (deg == 16) {
        const int q  = lane >> 4;
        const int f4 = lane & 15;

        // This quadrant's 4 scores (streamed once -> nontemporal).
        const f32x4* sp = (const f32x4*)(scores + start + (q << 2));
        f32x4 sv = __builtin_nontemporal_load(sp);

        // Wave-wide max over all 16 scores.
        float m = fmaxf(fmaxf(sv.x, sv.y), fmaxf(sv.z, sv.w));
        m = fmaxf(m, __shfl_xor(m, 16));
        m = fmaxf(m, __shfl_xor(m, 32));

        // exp only for this quadrant's 4 edges; wave-wide denom via shuffles.
        f32x4 w;
        w.x = __expf(sv.x - m);
        w.y = __expf(sv.y - m);
        w.z = __expf(sv.z - m);
        w.w = __expf(sv.w - m);
        float s = w.x + w.y + w.z + w.w;
        s += __shfl_xor(s, 16);
        s += __shfl_xor(s, 32);
        const float inv = 1.0f / s;

        // This quadrant's 4 column indices (streamed once).
        long long c0, c1, c2, c3;
        if (idx64) {
            const i64x2* ci = (const i64x2*)((const long long*)col_idx_v + start + (q << 2));
            i64x2 a = __builtin_nontemporal_load(ci);
            i64x2 b = __builtin_nontemporal_load(ci + 1);
            c0 = a.x; c1 = a.y; c2 = b.x; c3 = b.y;
        } else {
            const i32x4* ci = (const i32x4*)((const int*)col_idx_v + start + (q << 2));
            i32x4 cv = __builtin_nontemporal_load(ci);
            c0 = cv.x; c1 = cv.y; c2 = cv.z; c3 = cv.w;
        }

        // Gather 4 value rows (float4 per lane), weighted accumulate.
        const float* vb = values + (f4 << 2);
        f32x4 v0 = *(const f32x4*)(vb + (c0 << 6));
        f32x4 v1 = *(const f32x4*)(vb + (c1 << 6));
        f32x4 v2 = *(const f32x4*)(vb + (c2 << 6));
        f32x4 v3 = *(const f32x4*)(vb + (c3 << 6));

        f32x4 acc;
        acc.x = w.x * v0.x;              acc.y = w.x * v0.y;
        acc.z = w.x * v0.z;              acc.w = w.x * v0.w;
        acc.x = fmaf(w.y, v1.x, acc.x);  acc.y = fmaf(w.y, v1.y, acc.y);
        acc.z = fmaf(w.y, v1.z, acc.z);  acc.w = fmaf(w.y, v1.w, acc.w);
        acc.x = fmaf(w.z, v2.x, acc.x);  acc.y = fmaf(w.z, v2.y, acc.y);
        acc.z = fmaf(w.z, v2.z, acc.z);  acc.w = fmaf(w.z, v2.w, acc.w);
        acc.x = fmaf(w.w, v3.x, acc.x);  acc.y = fmaf(w.w, v3.y, acc.y);
        acc.z = fmaf(w.w, v3.z, acc.z);  acc.w = fmaf(w.w, v3.w, acc.w);

        // Sum partial results across the 4 quadrants.
        acc.x += __shfl_xor(acc.x, 16);  acc.x += __shfl_xor(acc.x, 32);
        acc.y += __shfl_xor(acc.y, 16);  acc.y += __shfl_xor(acc.y, 32);
        acc.z += __shfl_xor(acc.z, 16);  acc.z += __shfl_xor(acc.z, 32);
        acc.w += __shfl_xor(acc.w, 16);  acc.w += __shfl_xor(acc.w, 32);

        acc.x *= inv; acc.y *= inv; acc.z *= inv; acc.w *= inv;

        if (q == 0) {
            f32x4* op = (f32x4*)(out + (long long)wid * FEAT + (f4 << 2));
            __builtin_nontemporal_store(acc, op);
        }
    } else {
        // Generic fallback: lane = feature, any degree, either index width.
        float m = -INFINITY;
        for (long long e = start; e < end; ++e) m = fmaxf(m, scores[e]);
        float sum = 0.0f;
        for (long long e = start; e < end; ++e) sum += __expf(scores[e] - m);
        const float inv = (sum > 0.0f) ? 1.0f / sum : 0.0f;
        float acc = 0.0f;
        for (long long e = start; e < end; ++e) {
            long long c = idx64 ? ((const long long*)col_idx_v)[e]
                                : (long long)((const int*)col_idx_v)[e];
            acc += __expf(scores[e] - m) * values[c * FEAT + lane];
        }
        out[(long long)wid * FEAT + lane] = acc * inv;
    }
}

extern "C" void kernel_launch(void* const* d_in, const int* in_sizes, int n_in,
                              void* d_out, int out_size, void* d_ws, size_t ws_size,
                              hipStream_t stream) {
    const void*  row_ptr = d_in[0];
    const void*  col_idx = d_in[1];
    const float* scores  = (const float*)d_in[2];
    const float* values  = (const float*)d_in[3];
    float*       out     = (float*)d_out;

    const int num_nodes = in_sizes[0] - 1;  // 100000
    const int waves_per_block = 256 / 64;   // 4 nodes per block
    const int blocks = (num_nodes + waves_per_block - 1) / waves_per_block;

    hipLaunchKernelGGL(gat_agg_kernel, dim3(blocks), dim3(256), 0, stream,
                       row_ptr, col_idx, scores, values, out, num_nodes);
}